// Round 3
// baseline (484.075 us; speedup 1.0000x reference)
//
#include <hip/hip_runtime.h>

#define N_NODES 8192
#define HDIM    512
#define NEDGE   262144

typedef __attribute__((ext_vector_type(8))) short bf16x8;
typedef __attribute__((ext_vector_type(4))) short bf16x4;
typedef __attribute__((ext_vector_type(4))) float f32x4;

__device__ inline unsigned short f2bf(float f) {
  unsigned u = __float_as_uint(f);
  unsigned r = (u + 0x7FFFu + ((u >> 16) & 1u)) >> 16;
  return (unsigned short)r;
}
__device__ inline float bf2f(short s) {
  return __uint_as_float(((unsigned)(unsigned short)s) << 16);
}

__device__ inline void gload16(const void* g, void* l) {
  __builtin_amdgcn_global_load_lds(
      (const __attribute__((address_space(1))) unsigned*)g,
      (__attribute__((address_space(3))) unsigned*)l, 16, 0, 0);
}

// ---------------- CSR build ----------------
__global__ void zero_kernel(int* __restrict__ p) {
  p[blockIdx.x * 256 + threadIdx.x] = 0;
}

__global__ void hist_kernel(const int* __restrict__ rows, int* __restrict__ counts) {
  int e = blockIdx.x * 256 + threadIdx.x;
  atomicAdd(&counts[rows[e]], 1);
}

__global__ __launch_bounds__(1024) void scan_kernel(const int* __restrict__ counts,
                                                    int* __restrict__ offs,
                                                    int* __restrict__ cursor) {
  __shared__ int s[1024];
  int tid = threadIdx.x;
  int local[8];
  int sum = 0;
#pragma unroll
  for (int i = 0; i < 8; ++i) { local[i] = counts[tid * 8 + i]; sum += local[i]; }
  s[tid] = sum;
  __syncthreads();
  for (int d = 1; d < 1024; d <<= 1) {
    int v = (tid >= d) ? s[tid - d] : 0;
    __syncthreads();
    s[tid] += v;
    __syncthreads();
  }
  int base = (tid > 0) ? s[tid - 1] : 0;
#pragma unroll
  for (int i = 0; i < 8; ++i) {
    offs[tid * 8 + i] = base;
    cursor[tid * 8 + i] = base;
    base += local[i];
  }
  if (tid == 1023) offs[8192] = base;
}

__global__ void scatter_kernel(const int* __restrict__ rows, const int* __restrict__ cols,
                               const float* __restrict__ vals, int* cursor,
                               int* __restrict__ cols_s, float* __restrict__ vals_s) {
  int e = blockIdx.x * 256 + threadIdx.x;
  int slot = atomicAdd(&cursor[rows[e]], 1);
  cols_s[slot] = cols[e];
  vals_s[slot] = vals[e];
}

// ---------------- SpMM (CSR, 2 waves per row, bf16 gather, 4x unroll) -------
// MODE 0: prod = acc * aux (aux = x, f32)        -> prodb
// MODE 1: prod = acc * elu(aux) (aux = pre1 f32) -> prodb
// MODE 2: no product
template <int MODE>
__global__ __launch_bounds__(256) void spmm_bf(const int* __restrict__ offs,
                                               const int* __restrict__ cols_s,
                                               const float* __restrict__ vals_s,
                                               const short* __restrict__ Xbf,
                                               const float* __restrict__ aux,
                                               short* __restrict__ outb,
                                               short* __restrict__ prodb) {
  int wave = threadIdx.x >> 6;
  int row = blockIdx.x * 2 + (wave >> 1);
  int lane = threadIdx.x & 63;
  int h0 = (wave & 1) * 256 + lane * 4;
  float acc[4] = {0.f, 0.f, 0.f, 0.f};
  int e0 = offs[row], e1 = offs[row + 1];
  int p = e0;
  for (; p + 4 <= e1; p += 4) {
    float v0 = vals_s[p],     v1 = vals_s[p + 1];
    float v2 = vals_s[p + 2], v3 = vals_s[p + 3];
    int c0 = cols_s[p],     c1 = cols_s[p + 1];
    int c2 = cols_s[p + 2], c3 = cols_s[p + 3];
    bf16x4 x0 = *reinterpret_cast<const bf16x4*>(Xbf + (size_t)c0 * HDIM + h0);
    bf16x4 x1 = *reinterpret_cast<const bf16x4*>(Xbf + (size_t)c1 * HDIM + h0);
    bf16x4 x2 = *reinterpret_cast<const bf16x4*>(Xbf + (size_t)c2 * HDIM + h0);
    bf16x4 x3 = *reinterpret_cast<const bf16x4*>(Xbf + (size_t)c3 * HDIM + h0);
#pragma unroll
    for (int j = 0; j < 4; ++j) {
      acc[j] = fmaf(v0, bf2f(x0[j]), acc[j]);
      acc[j] = fmaf(v1, bf2f(x1[j]), acc[j]);
      acc[j] = fmaf(v2, bf2f(x2[j]), acc[j]);
      acc[j] = fmaf(v3, bf2f(x3[j]), acc[j]);
    }
  }
  for (; p < e1; ++p) {
    float v = vals_s[p];
    int c = cols_s[p];
    bf16x4 xr = *reinterpret_cast<const bf16x4*>(Xbf + (size_t)c * HDIM + h0);
#pragma unroll
    for (int j = 0; j < 4; ++j) acc[j] = fmaf(v, bf2f(xr[j]), acc[j]);
  }
  bf16x4 o;
#pragma unroll
  for (int j = 0; j < 4; ++j) o[j] = (short)f2bf(acc[j]);
  *reinterpret_cast<bf16x4*>(outb + (size_t)row * 1024 + h0) = o;
  if (MODE != 2) {
    float4 a0 = *reinterpret_cast<const float4*>(aux + (size_t)row * HDIM + h0);
    float xv[4] = {a0.x, a0.y, a0.z, a0.w};
    if (MODE == 1) {
#pragma unroll
      for (int j = 0; j < 4; ++j) xv[j] = xv[j] > 0.f ? xv[j] : expm1f(xv[j]);
    }
    bf16x4 t;
#pragma unroll
    for (int j = 0; j < 4; ++j) t[j] = (short)f2bf(acc[j] * xv[j]);
    *reinterpret_cast<bf16x4*>(prodb + (size_t)row * HDIM + h0) = t;
  }
}

// ---------------- f32 -> bf16 cast into strided dst ----------------
__global__ void cast_kernel(const float* __restrict__ src, short* __restrict__ dst,
                            int ld, int coloff) {
  int t = blockIdx.x * 256 + threadIdx.x;
  int row = t >> 6;
  int c0 = (t & 63) * 8;
  const float4* p = reinterpret_cast<const float4*>(src + (size_t)row * HDIM + c0);
  float4 a = p[0], b = p[1];
  bf16x8 o;
  o[0] = (short)f2bf(a.x); o[1] = (short)f2bf(a.y);
  o[2] = (short)f2bf(a.z); o[3] = (short)f2bf(a.w);
  o[4] = (short)f2bf(b.x); o[5] = (short)f2bf(b.y);
  o[6] = (short)f2bf(b.z); o[7] = (short)f2bf(b.w);
  *reinterpret_cast<bf16x8*>(dst + (size_t)row * ld + coloff + c0) = o;
}

__global__ void bias_kernel(const float* __restrict__ b1, const float* __restrict__ b2,
                            float* __restrict__ b12) {
  int j = blockIdx.x * 256 + threadIdx.x;
  if (j < HDIM) b12[j] = b1[j] + b2[j];
}

// ---------------- row L2 normalize + bf16 copy ----------------
__global__ __launch_bounds__(256) void rownorm_kernel(const float* __restrict__ X,
                                                      float* __restrict__ outf,
                                                      short* __restrict__ outb) {
  int row = blockIdx.x * 4 + (threadIdx.x >> 6);
  int lane = threadIdx.x & 63;
  int h0 = lane * 8;
  const float4* p = reinterpret_cast<const float4*>(X + (size_t)row * HDIM + h0);
  float4 a = p[0], b = p[1];
  float s = a.x * a.x + a.y * a.y + a.z * a.z + a.w * a.w +
            b.x * b.x + b.y * b.y + b.z * b.z + b.w * b.w;
#pragma unroll
  for (int off = 1; off < 64; off <<= 1) s += __shfl_xor(s, off, 64);
  float inv = 1.f / fmaxf(sqrtf(s), 1e-12f);
  a.x *= inv; a.y *= inv; a.z *= inv; a.w *= inv;
  b.x *= inv; b.y *= inv; b.z *= inv; b.w *= inv;
  float4* q = reinterpret_cast<float4*>(outf + (size_t)row * HDIM + h0);
  q[0] = a; q[1] = b;
  bf16x8 o;
  o[0] = (short)f2bf(a.x); o[1] = (short)f2bf(a.y);
  o[2] = (short)f2bf(a.z); o[3] = (short)f2bf(a.w);
  o[4] = (short)f2bf(b.x); o[5] = (short)f2bf(b.y);
  o[6] = (short)f2bf(b.z); o[7] = (short)f2bf(b.w);
  *reinterpret_cast<bf16x8*>(outb + (size_t)row * HDIM + h0) = o;
}

// ---------------- LDS-staged bf16 MFMA GEMM: C[M,N] = A[M,K] * B[N,K]^T ----
// 128x128 tile, BK=64, global_load_lds w=16, XOR chunk swizzle both sides.
// MODE 0: out0 = C + bias (pre, f32, ld N); out1bf = bf16(elu(pre))
// MODE 1: out0 = resid + 0.4*elu(C + bias)
// MODE 2: out0 = relu(C), SYMMETRIC (A==B): upper-tri blocks only, mirror via LDS
template <int MODE>
__global__ __launch_bounds__(256) void gemm_lds(const short* __restrict__ A,
                                                const short* __restrict__ B,
                                                int N, int K, int nbn,
                                                const float* __restrict__ bias,
                                                const float* __restrict__ resid,
                                                float* __restrict__ out0,
                                                short* __restrict__ out1bf) {
  __shared__ __align__(16) char smem[65536];
  short* la = (short*)smem;
  short* lb = (short*)(smem + 32768);
  float* tbuf = (float*)smem;   // reused after K-loop (MODE 2 mirror transpose)

  // bijective XCD swizzle (gridDim.x % 8 == 0 always here)
  int q = gridDim.x >> 3;
  int id = (blockIdx.x & 7) * q + (blockIdx.x >> 3);
  int bnI = id % nbn, bmI = id / nbn;
  if (MODE == 2 && bmI > bnI) return;   // symmetric: upper triangle only
  int bn = bnI * 128;
  int bm = bmI * 128;

  int lane = threadIdx.x & 63;
  int wave = threadIdx.x >> 6;

  // staging: segment s = wave*4 + j; lane covers linear byte s*1024 + lane*16
  // row r = s*8 + (lane>>3); physical chunk = lane&7; logical chunk = (lane&7)^(r&7)
  int rsub = lane >> 3;
  int csrc = (lane & 7) ^ rsub;
  size_t ldkB = (size_t)K * 2;
  const char* gA0 = (const char*)A + (size_t)(bm + wave * 32 + rsub) * ldkB + csrc * 16;
  const char* gB0 = (const char*)B + (size_t)(bn + wave * 32 + rsub) * ldkB + csrc * 16;
  char* lA0 = (char*)la + wave * 4096;
  char* lB0 = (char*)lb + wave * 4096;

  f32x4 zero = {0.f, 0.f, 0.f, 0.f};
  f32x4 acc[4][4];
#pragma unroll
  for (int m = 0; m < 4; ++m)
#pragma unroll
    for (int n = 0; n < 4; ++n) acc[m][n] = zero;

  int rlo = lane & 15;
  int khi = lane >> 4;
  int wm = wave >> 1, wn = wave & 1;

  for (int k0 = 0; k0 < K; k0 += 64) {
    __syncthreads();
#pragma unroll
    for (int j = 0; j < 4; ++j) {
      gload16(gA0 + (size_t)j * 8 * ldkB + (size_t)k0 * 2, lA0 + j * 1024);
      gload16(gB0 + (size_t)j * 8 * ldkB + (size_t)k0 * 2, lB0 + j * 1024);
    }
    __syncthreads();
#pragma unroll
    for (int kk = 0; kk < 2; ++kk) {
      bf16x8 av[4], bv[4];
#pragma unroll
      for (int m = 0; m < 4; ++m) {
        int ra = wm * 64 + m * 16 + rlo;
        int pc = (kk * 4 + khi) ^ (ra & 7);
        av[m] = *reinterpret_cast<const bf16x8*>((const char*)la + ra * 128 + pc * 16);
      }
#pragma unroll
      for (int n = 0; n < 4; ++n) {
        int rb = wn * 64 + n * 16 + rlo;
        int pc = (kk * 4 + khi) ^ (rb & 7);
        bv[n] = *reinterpret_cast<const bf16x8*>((const char*)lb + rb * 128 + pc * 16);
      }
#pragma unroll
      for (int m = 0; m < 4; ++m)
#pragma unroll
        for (int n = 0; n < 4; ++n)
          acc[m][n] = __builtin_amdgcn_mfma_f32_16x16x32_bf16(av[m], bv[n], acc[m][n], 0, 0, 0);
    }
  }

  int obm = bm + wm * 64;
  int obn = bn + wn * 64;
  int crow = (lane >> 4) * 4;
  int ccol = lane & 15;
#pragma unroll
  for (int n = 0; n < 4; ++n) {
    int c = obn + n * 16 + ccol;
    float bc = (MODE == 2) ? 0.f : bias[c];
#pragma unroll
    for (int m = 0; m < 4; ++m) {
#pragma unroll
      for (int v = 0; v < 4; ++v) {
        int r = obm + m * 16 + crow + v;
        size_t idx = (size_t)r * N + c;
        float val = acc[m][n][v];
        if (MODE == 0) {
          float pvl = val + bc;
          out0[idx] = pvl;
          float e = pvl > 0.f ? pvl : expm1f(pvl);
          out1bf[idx] = (short)f2bf(e);
        } else if (MODE == 1) {
          float pvl = val + bc;
          out0[idx] = resid[idx] + 0.4f * (pvl > 0.f ? pvl : expm1f(pvl));
        } else {
          out0[idx] = val > 0.f ? val : 0.f;
        }
      }
    }
  }

  // ---- MODE 2 off-diagonal: write transposed mirror block via LDS ----
  if (MODE == 2 && bmI < bnI) {
#pragma unroll
    for (int h = 0; h < 2; ++h) {
      __syncthreads();   // protect smem reuse (K-loop reads / previous half reads)
      if (wn == h) {
#pragma unroll
        for (int n = 0; n < 4; ++n) {
#pragma unroll
          for (int m = 0; m < 4; ++m) {
            float4 vv;
            vv.x = fmaxf(acc[m][n][0], 0.f);
            vv.y = fmaxf(acc[m][n][1], 0.f);
            vv.z = fmaxf(acc[m][n][2], 0.f);
            vv.w = fmaxf(acc[m][n][3], 0.f);
            // buf[row = n*16+ccol][col = wm*64 + m*16 + crow .. +3], ld 132
            *reinterpret_cast<float4*>(tbuf + (size_t)(n * 16 + ccol) * 132 +
                                       wm * 64 + m * 16 + crow) = vv;
          }
        }
      }
      __syncthreads();
      int i = threadIdx.x >> 2;           // 0..63  (mirror row within half)
      int j0 = (threadIdx.x & 3) * 32;    // col chunk
      float* dst = out0 + (size_t)(bn + h * 64 + i) * N + bm + j0;
      const float* srcb = tbuf + (size_t)i * 132 + j0;
#pragma unroll
      for (int jj = 0; jj < 32; jj += 4)
        *reinterpret_cast<float4*>(dst + jj) = *reinterpret_cast<const float4*>(srcb + jj);
    }
  }
}

extern "C" void kernel_launch(void* const* d_in, const int* in_sizes, int n_in,
                              void* d_out, int out_size, void* d_ws, size_t ws_size,
                              hipStream_t stream) {
  const float* x  = (const float*)d_in[0];
  const int* rows = (const int*)d_in[1];
  const int* cols = (const int*)d_in[2];
  const float* vals = (const float*)d_in[3];
  const float* W1 = (const float*)d_in[4];
  const float* b1 = (const float*)d_in[5];
  const float* W2 = (const float*)d_in[6];
  const float* b2 = (const float*)d_in[7];

  float* out_adj = (float*)d_out;
  float* out_hid = out_adj + (size_t)N_NODES * N_NODES;

  char* w = (char*)d_ws;
  size_t off = 0;
  auto alloc = [&](size_t bytes) -> void* {
    void* p = w + off;
    off += (bytes + 255) & ~(size_t)255;
    return p;
  };
  int* counts   = (int*)alloc(8192 * sizeof(int));
  int* offs     = (int*)alloc(8193 * sizeof(int));
  int* cursor   = (int*)alloc(8192 * sizeof(int));
  int* cols_s   = (int*)alloc((size_t)NEDGE * sizeof(int));
  float* vals_s = (float*)alloc((size_t)NEDGE * sizeof(float));
  float* b12    = (float*)alloc(HDIM * sizeof(float));
  short* Xbf    = (short*)alloc((size_t)N_NODES * HDIM * sizeof(short));
  short* Tbf    = (short*)alloc((size_t)N_NODES * HDIM * sizeof(short));
  short* Abuf   = (short*)alloc((size_t)N_NODES * 1024 * sizeof(short));
  short* Bbuf   = (short*)alloc((size_t)512 * 1024 * sizeof(short));
  float* pre1   = (float*)alloc((size_t)N_NODES * HDIM * sizeof(float));
  float* Hf     = (float*)alloc((size_t)N_NODES * HDIM * sizeof(float));
  short* Hbuf   = (short*)alloc((size_t)N_NODES * HDIM * sizeof(short));

  // CSR build (sorted cols/vals, no eidx indirection)
  zero_kernel<<<32, 256, 0, stream>>>(counts);
  hist_kernel<<<NEDGE / 256, 256, 0, stream>>>(rows, counts);
  scan_kernel<<<1, 1024, 0, stream>>>(counts, offs, cursor);
  scatter_kernel<<<NEDGE / 256, 256, 0, stream>>>(rows, cols, vals, cursor, cols_s, vals_s);

  // weights / bias / x prep
  bias_kernel<<<2, 256, 0, stream>>>(b1, b2, b12);
  cast_kernel<<<(512 * 64) / 256, 256, 0, stream>>>(W1, Bbuf, 1024, 0);
  cast_kernel<<<(512 * 64) / 256, 256, 0, stream>>>(W2, Bbuf, 1024, 512);
  cast_kernel<<<2048, 256, 0, stream>>>(x, Xbf, 512, 0);

  // ---- layer 1 ----
  spmm_bf<0><<<4096, 256, 0, stream>>>(offs, cols_s, vals_s, Xbf, x, Abuf, Tbf);
  spmm_bf<2><<<4096, 256, 0, stream>>>(offs, cols_s, vals_s, Tbf, nullptr, Abuf + 512, nullptr);
  // pre1 = [Ax|Axx]@[W1|W2]^T + b12 ; x1_bf = bf16(elu(pre1)) -> Xbf (reuse)
  gemm_lds<0><<<256, 256, 0, stream>>>(Abuf, Bbuf, 512, 1024, 4, b12, nullptr, pre1, Xbf);

  // ---- layer 2 ----
  spmm_bf<1><<<4096, 256, 0, stream>>>(offs, cols_s, vals_s, Xbf, pre1, Abuf, Tbf);
  spmm_bf<2><<<4096, 256, 0, stream>>>(offs, cols_s, vals_s, Tbf, nullptr, Abuf + 512, nullptr);
  // x2 = pre1 + 0.4*elu([Ax2|Axx2]@[W1|W2]^T + b12) -> Hf
  gemm_lds<1><<<256, 256, 0, stream>>>(Abuf, Bbuf, 512, 1024, 4, b12, pre1, Hf, nullptr);

  // ---- decoder ----
  rownorm_kernel<<<2048, 256, 0, stream>>>(Hf, out_hid, Hbuf);
  gemm_lds<2><<<4096, 256, 0, stream>>>(Hbuf, Hbuf, 8192, 512, 64, nullptr, nullptr, out_adj, nullptr);
}

// Round 4
// 361.402 us; speedup vs baseline: 1.3394x; 1.3394x over previous
//
#include <hip/hip_runtime.h>

#define N_NODES 8192
#define HDIM    512
#define NEDGE   262144

typedef __attribute__((ext_vector_type(8))) short bf16x8;
typedef __attribute__((ext_vector_type(4))) float f32x4;

__device__ inline unsigned short f2bf(float f) {
  unsigned u = __float_as_uint(f);
  unsigned r = (u + 0x7FFFu + ((u >> 16) & 1u)) >> 16;
  return (unsigned short)r;
}
__device__ inline float bf2f(short s) {
  return __uint_as_float(((unsigned)(unsigned short)s) << 16);
}

__device__ inline void gload16(const void* g, void* l) {
  __builtin_amdgcn_global_load_lds(
      (const __attribute__((address_space(1))) unsigned*)g,
      (__attribute__((address_space(3))) unsigned*)l, 16, 0, 0);
}

// ---------------- CSR build ----------------
__global__ void zero_kernel(int* __restrict__ p) {
  p[blockIdx.x * 256 + threadIdx.x] = 0;
}

__global__ void hist_kernel(const int* __restrict__ rows, int* __restrict__ counts) {
  int e = blockIdx.x * 256 + threadIdx.x;
  atomicAdd(&counts[rows[e]], 1);
}

__global__ __launch_bounds__(1024) void scan_kernel(const int* __restrict__ counts,
                                                    int* __restrict__ offs,
                                                    int* __restrict__ cursor) {
  __shared__ int s[1024];
  int tid = threadIdx.x;
  int local[8];
  int sum = 0;
#pragma unroll
  for (int i = 0; i < 8; ++i) { local[i] = counts[tid * 8 + i]; sum += local[i]; }
  s[tid] = sum;
  __syncthreads();
  for (int d = 1; d < 1024; d <<= 1) {
    int v = (tid >= d) ? s[tid - d] : 0;
    __syncthreads();
    s[tid] += v;
    __syncthreads();
  }
  int base = (tid > 0) ? s[tid - 1] : 0;
#pragma unroll
  for (int i = 0; i < 8; ++i) {
    offs[tid * 8 + i] = base;
    cursor[tid * 8 + i] = base;
    base += local[i];
  }
  if (tid == 1023) offs[8192] = base;
}

__global__ void scatter_kernel(const int* __restrict__ rows, const int* __restrict__ cols,
                               const float* __restrict__ vals, int* cursor,
                               int2* __restrict__ edges) {
  int e = blockIdx.x * 256 + threadIdx.x;
  int slot = atomicAdd(&cursor[rows[e]], 1);
  edges[slot] = make_int2(cols[e], __float_as_int(vals[e]));
}

// ---------------- SpMM (CSR, wave per row, bf16x8 gather, 8x unroll) --------
// MODE 0: prod = acc * aux (aux = x, f32)        -> prodb
// MODE 1: prod = acc * elu(aux) (aux = pre1 f32) -> prodb
// MODE 2: no product
template <int MODE>
__global__ __launch_bounds__(256) void spmm_bf(const int* __restrict__ offs,
                                               const int2* __restrict__ edges,
                                               const short* __restrict__ Xbf,
                                               const float* __restrict__ aux,
                                               short* __restrict__ outb,
                                               short* __restrict__ prodb) {
  int row = blockIdx.x * 4 + (threadIdx.x >> 6);
  int lane = threadIdx.x & 63;
  int h0 = lane * 8;
  float acc[8] = {0.f, 0.f, 0.f, 0.f, 0.f, 0.f, 0.f, 0.f};
  int e0 = offs[row], e1 = offs[row + 1];
  int p = e0;
  for (; p + 8 <= e1; p += 8) {
    int2 e[8];
#pragma unroll
    for (int u = 0; u < 8; ++u) e[u] = edges[p + u];
    bf16x8 xv[8];
#pragma unroll
    for (int u = 0; u < 8; ++u)
      xv[u] = *reinterpret_cast<const bf16x8*>(Xbf + (size_t)e[u].x * HDIM + h0);
#pragma unroll
    for (int u = 0; u < 8; ++u) {
      float v = __int_as_float(e[u].y);
#pragma unroll
      for (int j = 0; j < 8; ++j) acc[j] = fmaf(v, bf2f(xv[u][j]), acc[j]);
    }
  }
  for (; p < e1; ++p) {
    int2 e = edges[p];
    float v = __int_as_float(e.y);
    bf16x8 xr = *reinterpret_cast<const bf16x8*>(Xbf + (size_t)e.x * HDIM + h0);
#pragma unroll
    for (int j = 0; j < 8; ++j) acc[j] = fmaf(v, bf2f(xr[j]), acc[j]);
  }
  bf16x8 o;
#pragma unroll
  for (int j = 0; j < 8; ++j) o[j] = (short)f2bf(acc[j]);
  *reinterpret_cast<bf16x8*>(outb + (size_t)row * 1024 + h0) = o;
  if (MODE != 2) {
    const float4* ap = reinterpret_cast<const float4*>(aux + (size_t)row * HDIM + h0);
    float4 a0 = ap[0], a1 = ap[1];
    float xv[8] = {a0.x, a0.y, a0.z, a0.w, a1.x, a1.y, a1.z, a1.w};
    if (MODE == 1) {
#pragma unroll
      for (int j = 0; j < 8; ++j) xv[j] = xv[j] > 0.f ? xv[j] : expm1f(xv[j]);
    }
    bf16x8 t;
#pragma unroll
    for (int j = 0; j < 8; ++j) t[j] = (short)f2bf(acc[j] * xv[j]);
    *reinterpret_cast<bf16x8*>(prodb + (size_t)row * HDIM + h0) = t;
  }
}

// ---------------- f32 -> bf16 cast into strided dst ----------------
__global__ void cast_kernel(const float* __restrict__ src, short* __restrict__ dst,
                            int ld, int coloff) {
  int t = blockIdx.x * 256 + threadIdx.x;
  int row = t >> 6;
  int c0 = (t & 63) * 8;
  const float4* p = reinterpret_cast<const float4*>(src + (size_t)row * HDIM + c0);
  float4 a = p[0], b = p[1];
  bf16x8 o;
  o[0] = (short)f2bf(a.x); o[1] = (short)f2bf(a.y);
  o[2] = (short)f2bf(a.z); o[3] = (short)f2bf(a.w);
  o[4] = (short)f2bf(b.x); o[5] = (short)f2bf(b.y);
  o[6] = (short)f2bf(b.z); o[7] = (short)f2bf(b.w);
  *reinterpret_cast<bf16x8*>(dst + (size_t)row * ld + coloff + c0) = o;
}

__global__ void bias_kernel(const float* __restrict__ b1, const float* __restrict__ b2,
                            float* __restrict__ b12) {
  int j = blockIdx.x * 256 + threadIdx.x;
  if (j < HDIM) b12[j] = b1[j] + b2[j];
}

// ---------------- row L2 normalize + bf16 copy ----------------
__global__ __launch_bounds__(256) void rownorm_kernel(const float* __restrict__ X,
                                                      float* __restrict__ outf,
                                                      short* __restrict__ outb) {
  int row = blockIdx.x * 4 + (threadIdx.x >> 6);
  int lane = threadIdx.x & 63;
  int h0 = lane * 8;
  const float4* p = reinterpret_cast<const float4*>(X + (size_t)row * HDIM + h0);
  float4 a = p[0], b = p[1];
  float s = a.x * a.x + a.y * a.y + a.z * a.z + a.w * a.w +
            b.x * b.x + b.y * b.y + b.z * b.z + b.w * b.w;
#pragma unroll
  for (int off = 1; off < 64; off <<= 1) s += __shfl_xor(s, off, 64);
  float inv = 1.f / fmaxf(sqrtf(s), 1e-12f);
  a.x *= inv; a.y *= inv; a.z *= inv; a.w *= inv;
  b.x *= inv; b.y *= inv; b.z *= inv; b.w *= inv;
  float4* q = reinterpret_cast<float4*>(outf + (size_t)row * HDIM + h0);
  q[0] = a; q[1] = b;
  bf16x8 o;
  o[0] = (short)f2bf(a.x); o[1] = (short)f2bf(a.y);
  o[2] = (short)f2bf(a.z); o[3] = (short)f2bf(a.w);
  o[4] = (short)f2bf(b.x); o[5] = (short)f2bf(b.y);
  o[6] = (short)f2bf(b.z); o[7] = (short)f2bf(b.w);
  *reinterpret_cast<bf16x8*>(outb + (size_t)row * HDIM + h0) = o;
}

// ---------------- LDS-staged bf16 MFMA GEMM: C[M,N] = A[M,K] * B[N,K]^T ----
// 128x128 tile, BK=64, global_load_lds w=16, XOR chunk swizzle both sides.
// MODE 0: out0 = C + bias (pre, f32, ld N); out1bf = bf16(elu(pre))
// MODE 1: out0 = resid + 0.4*elu(C + bias)
// MODE 2: out0 = relu(C)
template <int MODE>
__global__ __launch_bounds__(256) void gemm_lds(const short* __restrict__ A,
                                                const short* __restrict__ B,
                                                int N, int K, int nbn,
                                                const float* __restrict__ bias,
                                                const float* __restrict__ resid,
                                                float* __restrict__ out0,
                                                short* __restrict__ out1bf) {
  __shared__ __align__(16) short la[128 * 64];
  __shared__ __align__(16) short lb[128 * 64];

  // bijective XCD swizzle (gridDim.x % 8 == 0 always here)
  int q = gridDim.x >> 3;
  int id = (blockIdx.x & 7) * q + (blockIdx.x >> 3);
  int bn = (id % nbn) * 128;
  int bm = (id / nbn) * 128;

  int lane = threadIdx.x & 63;
  int wave = threadIdx.x >> 6;

  // staging: segment s = wave*4 + j; lane covers linear byte s*1024 + lane*16
  // row r = s*8 + (lane>>3); physical chunk = lane&7; logical chunk = (lane&7)^(r&7)
  int rsub = lane >> 3;
  int csrc = (lane & 7) ^ rsub;
  size_t ldkB = (size_t)K * 2;
  const char* gA0 = (const char*)A + (size_t)(bm + wave * 32 + rsub) * ldkB + csrc * 16;
  const char* gB0 = (const char*)B + (size_t)(bn + wave * 32 + rsub) * ldkB + csrc * 16;
  char* lA0 = (char*)la + wave * 4096;
  char* lB0 = (char*)lb + wave * 4096;

  f32x4 zero = {0.f, 0.f, 0.f, 0.f};
  f32x4 acc[4][4];
#pragma unroll
  for (int m = 0; m < 4; ++m)
#pragma unroll
    for (int n = 0; n < 4; ++n) acc[m][n] = zero;

  int rlo = lane & 15;
  int khi = lane >> 4;
  int wm = wave >> 1, wn = wave & 1;

  for (int k0 = 0; k0 < K; k0 += 64) {
    __syncthreads();
#pragma unroll
    for (int j = 0; j < 4; ++j) {
      gload16(gA0 + (size_t)j * 8 * ldkB + (size_t)k0 * 2, lA0 + j * 1024);
      gload16(gB0 + (size_t)j * 8 * ldkB + (size_t)k0 * 2, lB0 + j * 1024);
    }
    __syncthreads();
#pragma unroll
    for (int kk = 0; kk < 2; ++kk) {
      bf16x8 av[4], bv[4];
#pragma unroll
      for (int m = 0; m < 4; ++m) {
        int ra = wm * 64 + m * 16 + rlo;
        int pc = (kk * 4 + khi) ^ (ra & 7);
        av[m] = *reinterpret_cast<const bf16x8*>((const char*)la + ra * 128 + pc * 16);
      }
#pragma unroll
      for (int n = 0; n < 4; ++n) {
        int rb = wn * 64 + n * 16 + rlo;
        int pc = (kk * 4 + khi) ^ (rb & 7);
        bv[n] = *reinterpret_cast<const bf16x8*>((const char*)lb + rb * 128 + pc * 16);
      }
#pragma unroll
      for (int m = 0; m < 4; ++m)
#pragma unroll
        for (int n = 0; n < 4; ++n)
          acc[m][n] = __builtin_amdgcn_mfma_f32_16x16x32_bf16(av[m], bv[n], acc[m][n], 0, 0, 0);
    }
  }

  int obm = bm + wm * 64;
  int obn = bn + wn * 64;
  int crow = (lane >> 4) * 4;
  int ccol = lane & 15;
#pragma unroll
  for (int n = 0; n < 4; ++n) {
    int c = obn + n * 16 + ccol;
    float bc = (MODE == 2) ? 0.f : bias[c];
#pragma unroll
    for (int m = 0; m < 4; ++m) {
#pragma unroll
      for (int v = 0; v < 4; ++v) {
        int r = obm + m * 16 + crow + v;
        size_t idx = (size_t)r * N + c;
        float val = acc[m][n][v];
        if (MODE == 0) {
          float pvl = val + bc;
          out0[idx] = pvl;
          float e = pvl > 0.f ? pvl : expm1f(pvl);
          out1bf[idx] = (short)f2bf(e);
        } else if (MODE == 1) {
          float pvl = val + bc;
          out0[idx] = resid[idx] + 0.4f * (pvl > 0.f ? pvl : expm1f(pvl));
        } else {
          out0[idx] = val > 0.f ? val : 0.f;
        }
      }
    }
  }
}

extern "C" void kernel_launch(void* const* d_in, const int* in_sizes, int n_in,
                              void* d_out, int out_size, void* d_ws, size_t ws_size,
                              hipStream_t stream) {
  const float* x  = (const float*)d_in[0];
  const int* rows = (const int*)d_in[1];
  const int* cols = (const int*)d_in[2];
  const float* vals = (const float*)d_in[3];
  const float* W1 = (const float*)d_in[4];
  const float* b1 = (const float*)d_in[5];
  const float* W2 = (const float*)d_in[6];
  const float* b2 = (const float*)d_in[7];

  float* out_adj = (float*)d_out;
  float* out_hid = out_adj + (size_t)N_NODES * N_NODES;

  char* w = (char*)d_ws;
  size_t off = 0;
  auto alloc = [&](size_t bytes) -> void* {
    void* p = w + off;
    off += (bytes + 255) & ~(size_t)255;
    return p;
  };
  int* counts   = (int*)alloc(8192 * sizeof(int));
  int* offs     = (int*)alloc(8193 * sizeof(int));
  int* cursor   = (int*)alloc(8192 * sizeof(int));
  int2* edges   = (int2*)alloc((size_t)NEDGE * sizeof(int2));
  float* b12    = (float*)alloc(HDIM * sizeof(float));
  short* Xbf    = (short*)alloc((size_t)N_NODES * HDIM * sizeof(short));
  short* Tbf    = (short*)alloc((size_t)N_NODES * HDIM * sizeof(short));
  short* Abuf   = (short*)alloc((size_t)N_NODES * 1024 * sizeof(short));
  short* Bbuf   = (short*)alloc((size_t)512 * 1024 * sizeof(short));
  float* pre1   = (float*)alloc((size_t)N_NODES * HDIM * sizeof(float));
  float* Hf     = (float*)alloc((size_t)N_NODES * HDIM * sizeof(float));
  short* Hbuf   = (short*)alloc((size_t)N_NODES * HDIM * sizeof(short));

  // CSR build (packed (col,val) edge list, row-sorted)
  zero_kernel<<<32, 256, 0, stream>>>(counts);
  hist_kernel<<<NEDGE / 256, 256, 0, stream>>>(rows, counts);
  scan_kernel<<<1, 1024, 0, stream>>>(counts, offs, cursor);
  scatter_kernel<<<NEDGE / 256, 256, 0, stream>>>(rows, cols, vals, cursor, edges);

  // weights / bias / x prep
  bias_kernel<<<2, 256, 0, stream>>>(b1, b2, b12);
  cast_kernel<<<(512 * 64) / 256, 256, 0, stream>>>(W1, Bbuf, 1024, 0);
  cast_kernel<<<(512 * 64) / 256, 256, 0, stream>>>(W2, Bbuf, 1024, 512);
  cast_kernel<<<2048, 256, 0, stream>>>(x, Xbf, 512, 0);

  // ---- layer 1 ----
  spmm_bf<0><<<2048, 256, 0, stream>>>(offs, edges, Xbf, x, Abuf, Tbf);
  spmm_bf<2><<<2048, 256, 0, stream>>>(offs, edges, Tbf, nullptr, Abuf + 512, nullptr);
  // pre1 = [Ax|Axx]@[W1|W2]^T + b12 ; x1_bf = bf16(elu(pre1)) -> Xbf (reuse)
  gemm_lds<0><<<256, 256, 0, stream>>>(Abuf, Bbuf, 512, 1024, 4, b12, nullptr, pre1, Xbf);

  // ---- layer 2 ----
  spmm_bf<1><<<2048, 256, 0, stream>>>(offs, edges, Xbf, pre1, Abuf, Tbf);
  spmm_bf<2><<<2048, 256, 0, stream>>>(offs, edges, Tbf, nullptr, Abuf + 512, nullptr);
  // x2 = pre1 + 0.4*elu([Ax2|Axx2]@[W1|W2]^T + b12) -> Hf
  gemm_lds<1><<<256, 256, 0, stream>>>(Abuf, Bbuf, 512, 1024, 4, b12, pre1, Hf, nullptr);

  // ---- decoder ----
  rownorm_kernel<<<2048, 256, 0, stream>>>(Hf, out_hid, Hbuf);
  gemm_lds<2><<<4096, 256, 0, stream>>>(Hbuf, Hbuf, 8192, 512, 64, nullptr, nullptr, out_adj, nullptr);
}

// Round 5
// 328.158 us; speedup vs baseline: 1.4751x; 1.1013x over previous
//
#include <hip/hip_runtime.h>

#define N_NODES 8192
#define HDIM    512
#define NEDGE   262144

typedef __attribute__((ext_vector_type(8))) short bf16x8;
typedef __attribute__((ext_vector_type(4))) float f32x4;

__device__ inline unsigned short f2bf(float f) {
  unsigned u = __float_as_uint(f);
  unsigned r = (u + 0x7FFFu + ((u >> 16) & 1u)) >> 16;
  return (unsigned short)r;
}
__device__ inline float bf2f(short s) {
  return __uint_as_float(((unsigned)(unsigned short)s) << 16);
}

__device__ inline void gload16(const void* g, void* l) {
  __builtin_amdgcn_global_load_lds(
      (const __attribute__((address_space(1))) unsigned*)g,
      (__attribute__((address_space(3))) unsigned*)l, 16, 0, 0);
}

// ---------------- CSR build ----------------
__global__ void zero_kernel(int* __restrict__ p) {
  p[blockIdx.x * 256 + threadIdx.x] = 0;
}

__global__ void hist_kernel(const int* __restrict__ rows, int* __restrict__ counts) {
  int e = blockIdx.x * 256 + threadIdx.x;
  atomicAdd(&counts[rows[e]], 1);
}

__global__ __launch_bounds__(1024) void scan_kernel(const int* __restrict__ counts,
                                                    int* __restrict__ offs,
                                                    int* __restrict__ cursor) {
  __shared__ int s[1024];
  int tid = threadIdx.x;
  int local[8];
  int sum = 0;
#pragma unroll
  for (int i = 0; i < 8; ++i) { local[i] = counts[tid * 8 + i]; sum += local[i]; }
  s[tid] = sum;
  __syncthreads();
  for (int d = 1; d < 1024; d <<= 1) {
    int v = (tid >= d) ? s[tid - d] : 0;
    __syncthreads();
    s[tid] += v;
    __syncthreads();
  }
  int base = (tid > 0) ? s[tid - 1] : 0;
#pragma unroll
  for (int i = 0; i < 8; ++i) {
    offs[tid * 8 + i] = base;
    cursor[tid * 8 + i] = base;
    base += local[i];
  }
  if (tid == 1023) offs[8192] = base;
}

__global__ void scatter_kernel(const int* __restrict__ rows, const int* __restrict__ cols,
                               const float* __restrict__ vals, int* cursor,
                               int2* __restrict__ edges) {
  int e = blockIdx.x * 256 + threadIdx.x;
  int slot = atomicAdd(&cursor[rows[e]], 1);
  edges[slot] = make_int2(cols[e], __float_as_int(vals[e]));
}

// ---------------- SpMM (CSR, wave/row, 4-wide 2-stage reg pipeline) ---------
// MODE 0: prod = acc * aux (aux = x, f32)        -> prodb
// MODE 1: prod = acc * elu(aux) (aux = pre1 f32) -> prodb
// MODE 2: no product
template <int MODE>
__global__ __launch_bounds__(256) void spmm_bf(const int* __restrict__ offs,
                                               const int2* __restrict__ edges,
                                               const short* __restrict__ Xbf,
                                               const float* __restrict__ aux,
                                               short* __restrict__ outb,
                                               short* __restrict__ prodb) {
  int row = blockIdx.x * 4 + (threadIdx.x >> 6);
  int lane = threadIdx.x & 63;
  int h0 = lane * 8;
  float acc[8] = {0.f, 0.f, 0.f, 0.f, 0.f, 0.f, 0.f, 0.f};
  int e0 = offs[row], e1 = offs[row + 1];
  int p = e0;

  int2 ma0, ma1, ma2, ma3;
  bf16x8 xa0, xa1, xa2, xa3;

  if (p + 4 <= e1) {
    ma0 = edges[p]; ma1 = edges[p + 1]; ma2 = edges[p + 2]; ma3 = edges[p + 3];
    xa0 = *reinterpret_cast<const bf16x8*>(Xbf + (size_t)ma0.x * HDIM + h0);
    xa1 = *reinterpret_cast<const bf16x8*>(Xbf + (size_t)ma1.x * HDIM + h0);
    xa2 = *reinterpret_cast<const bf16x8*>(Xbf + (size_t)ma2.x * HDIM + h0);
    xa3 = *reinterpret_cast<const bf16x8*>(Xbf + (size_t)ma3.x * HDIM + h0);
    p += 4;
    for (; p + 4 <= e1; p += 4) {
      // issue next stage BEFORE consuming current (keeps ~8 loads in flight)
      int2 mb0 = edges[p], mb1 = edges[p + 1], mb2 = edges[p + 2], mb3 = edges[p + 3];
      bf16x8 xb0 = *reinterpret_cast<const bf16x8*>(Xbf + (size_t)mb0.x * HDIM + h0);
      bf16x8 xb1 = *reinterpret_cast<const bf16x8*>(Xbf + (size_t)mb1.x * HDIM + h0);
      bf16x8 xb2 = *reinterpret_cast<const bf16x8*>(Xbf + (size_t)mb2.x * HDIM + h0);
      bf16x8 xb3 = *reinterpret_cast<const bf16x8*>(Xbf + (size_t)mb3.x * HDIM + h0);
      float v0 = __int_as_float(ma0.y), v1 = __int_as_float(ma1.y);
      float v2 = __int_as_float(ma2.y), v3 = __int_as_float(ma3.y);
#pragma unroll
      for (int j = 0; j < 8; ++j) {
        acc[j] = fmaf(v0, bf2f(xa0[j]), acc[j]);
        acc[j] = fmaf(v1, bf2f(xa1[j]), acc[j]);
        acc[j] = fmaf(v2, bf2f(xa2[j]), acc[j]);
        acc[j] = fmaf(v3, bf2f(xa3[j]), acc[j]);
      }
      ma0 = mb0; ma1 = mb1; ma2 = mb2; ma3 = mb3;
      xa0 = xb0; xa1 = xb1; xa2 = xb2; xa3 = xb3;
    }
    {
      float v0 = __int_as_float(ma0.y), v1 = __int_as_float(ma1.y);
      float v2 = __int_as_float(ma2.y), v3 = __int_as_float(ma3.y);
#pragma unroll
      for (int j = 0; j < 8; ++j) {
        acc[j] = fmaf(v0, bf2f(xa0[j]), acc[j]);
        acc[j] = fmaf(v1, bf2f(xa1[j]), acc[j]);
        acc[j] = fmaf(v2, bf2f(xa2[j]), acc[j]);
        acc[j] = fmaf(v3, bf2f(xa3[j]), acc[j]);
      }
    }
  }
  for (; p < e1; ++p) {
    int2 e = edges[p];
    float v = __int_as_float(e.y);
    bf16x8 xr = *reinterpret_cast<const bf16x8*>(Xbf + (size_t)e.x * HDIM + h0);
#pragma unroll
    for (int j = 0; j < 8; ++j) acc[j] = fmaf(v, bf2f(xr[j]), acc[j]);
  }

  bf16x8 o;
#pragma unroll
  for (int j = 0; j < 8; ++j) o[j] = (short)f2bf(acc[j]);
  *reinterpret_cast<bf16x8*>(outb + (size_t)row * 1024 + h0) = o;
  if (MODE != 2) {
    const float4* ap = reinterpret_cast<const float4*>(aux + (size_t)row * HDIM + h0);
    float4 a0 = ap[0], a1 = ap[1];
    float xv[8] = {a0.x, a0.y, a0.z, a0.w, a1.x, a1.y, a1.z, a1.w};
    if (MODE == 1) {
#pragma unroll
      for (int j = 0; j < 8; ++j) xv[j] = xv[j] > 0.f ? xv[j] : expm1f(xv[j]);
    }
    bf16x8 t;
#pragma unroll
    for (int j = 0; j < 8; ++j) t[j] = (short)f2bf(acc[j] * xv[j]);
    *reinterpret_cast<bf16x8*>(prodb + (size_t)row * HDIM + h0) = t;
  }
}

// ---------------- fused prep: x cast + W1/W2 cast + bias ----------------
__device__ inline void cast8(const float* src, short* dst) {
  const float4* p = reinterpret_cast<const float4*>(src);
  float4 a = p[0], b = p[1];
  bf16x8 o;
  o[0] = (short)f2bf(a.x); o[1] = (short)f2bf(a.y);
  o[2] = (short)f2bf(a.z); o[3] = (short)f2bf(a.w);
  o[4] = (short)f2bf(b.x); o[5] = (short)f2bf(b.y);
  o[6] = (short)f2bf(b.z); o[7] = (short)f2bf(b.w);
  *reinterpret_cast<bf16x8*>(dst) = o;
}

__global__ void prep_kernel(const float* __restrict__ x,
                            const float* __restrict__ W1, const float* __restrict__ W2,
                            const float* __restrict__ b1, const float* __restrict__ b2,
                            short* __restrict__ Xbf, short* __restrict__ Bbuf,
                            float* __restrict__ b12) {
  int b = blockIdx.x;
  if (b < 2048) {                 // x: 8192x512 -> Xbf (ld 512)
    int t = b * 256 + threadIdx.x;
    int row = t >> 6, c0 = (t & 63) * 8;
    cast8(x + (size_t)row * 512 + c0, Xbf + (size_t)row * 512 + c0);
  } else if (b < 2176) {          // W1: 512x512 -> Bbuf col 0 (ld 1024)
    int t = (b - 2048) * 256 + threadIdx.x;
    int row = t >> 6, c0 = (t & 63) * 8;
    cast8(W1 + (size_t)row * 512 + c0, Bbuf + (size_t)row * 1024 + c0);
  } else if (b < 2304) {          // W2 -> Bbuf col 512
    int t = (b - 2176) * 256 + threadIdx.x;
    int row = t >> 6, c0 = (t & 63) * 8;
    cast8(W2 + (size_t)row * 512 + c0, Bbuf + (size_t)row * 1024 + 512 + c0);
  } else {                        // bias
    int j = threadIdx.x;
    b12[j] = b1[j] + b2[j];
    b12[j + 256] = b1[j + 256] + b2[j + 256];
  }
}

// ---------------- row L2 normalize + bf16 copy ----------------
__global__ __launch_bounds__(256) void rownorm_kernel(const float* __restrict__ X,
                                                      float* __restrict__ outf,
                                                      short* __restrict__ outb) {
  int row = blockIdx.x * 4 + (threadIdx.x >> 6);
  int lane = threadIdx.x & 63;
  int h0 = lane * 8;
  const float4* p = reinterpret_cast<const float4*>(X + (size_t)row * HDIM + h0);
  float4 a = p[0], b = p[1];
  float s = a.x * a.x + a.y * a.y + a.z * a.z + a.w * a.w +
            b.x * b.x + b.y * b.y + b.z * b.z + b.w * b.w;
#pragma unroll
  for (int off = 1; off < 64; off <<= 1) s += __shfl_xor(s, off, 64);
  float inv = 1.f / fmaxf(sqrtf(s), 1e-12f);
  a.x *= inv; a.y *= inv; a.z *= inv; a.w *= inv;
  b.x *= inv; b.y *= inv; b.z *= inv; b.w *= inv;
  float4* q = reinterpret_cast<float4*>(outf + (size_t)row * HDIM + h0);
  q[0] = a; q[1] = b;
  bf16x8 o;
  o[0] = (short)f2bf(a.x); o[1] = (short)f2bf(a.y);
  o[2] = (short)f2bf(a.z); o[3] = (short)f2bf(a.w);
  o[4] = (short)f2bf(b.x); o[5] = (short)f2bf(b.y);
  o[6] = (short)f2bf(b.z); o[7] = (short)f2bf(b.w);
  *reinterpret_cast<bf16x8*>(outb + (size_t)row * HDIM + h0) = o;
}

// ---------------- LDS-staged bf16 MFMA GEMM: C[M,N] = A[M,K] * B[N,K]^T ----
// 128x128 tile, BK=64, global_load_lds w=16, XOR chunk swizzle both sides.
// MODE 0: out0 = C + bias (pre, f32, ld N); out1bf = bf16(elu(pre))
// MODE 1: out0 = resid + 0.4*elu(C + bias)
// MODE 2: out0 = relu(C); 8x8 supertile block mapping for L2 locality
template <int MODE>
__global__ __launch_bounds__(256) void gemm_lds(const short* __restrict__ A,
                                                const short* __restrict__ B,
                                                int N, int K, int nbn,
                                                const float* __restrict__ bias,
                                                const float* __restrict__ resid,
                                                float* __restrict__ out0,
                                                short* __restrict__ out1bf) {
  __shared__ __align__(16) short la[128 * 64];
  __shared__ __align__(16) short lb[128 * 64];

  // bijective XCD swizzle (gridDim.x % 8 == 0 always here)
  int q = gridDim.x >> 3;
  int id = (blockIdx.x & 7) * q + (blockIdx.x >> 3);
  int bn, bm;
  if (MODE == 2) {
    // 8x8 block supertiles: each XCD works one supertile (1MB A + 1MB B,
    // both L2-resident) at a time; consecutive supertiles share A rows.
    int sid = id >> 6, wid = id & 63;
    int srow = sid >> 3, scol = sid & 7;
    bm = (srow * 8 + (wid >> 3)) * 128;
    bn = (scol * 8 + (wid & 7)) * 128;
  } else {
    bn = (id % nbn) * 128;
    bm = (id / nbn) * 128;
  }

  int lane = threadIdx.x & 63;
  int wave = threadIdx.x >> 6;

  // staging: segment s = wave*4 + j; lane covers linear byte s*1024 + lane*16
  // row r = s*8 + (lane>>3); physical chunk = lane&7; logical chunk = (lane&7)^(r&7)
  int rsub = lane >> 3;
  int csrc = (lane & 7) ^ rsub;
  size_t ldkB = (size_t)K * 2;
  const char* gA0 = (const char*)A + (size_t)(bm + wave * 32 + rsub) * ldkB + csrc * 16;
  const char* gB0 = (const char*)B + (size_t)(bn + wave * 32 + rsub) * ldkB + csrc * 16;
  char* lA0 = (char*)la + wave * 4096;
  char* lB0 = (char*)lb + wave * 4096;

  f32x4 zero = {0.f, 0.f, 0.f, 0.f};
  f32x4 acc[4][4];
#pragma unroll
  for (int m = 0; m < 4; ++m)
#pragma unroll
    for (int n = 0; n < 4; ++n) acc[m][n] = zero;

  int rlo = lane & 15;
  int khi = lane >> 4;
  int wm = wave >> 1, wn = wave & 1;

  for (int k0 = 0; k0 < K; k0 += 64) {
    __syncthreads();
#pragma unroll
    for (int j = 0; j < 4; ++j) {
      gload16(gA0 + (size_t)j * 8 * ldkB + (size_t)k0 * 2, lA0 + j * 1024);
      gload16(gB0 + (size_t)j * 8 * ldkB + (size_t)k0 * 2, lB0 + j * 1024);
    }
    __syncthreads();
#pragma unroll
    for (int kk = 0; kk < 2; ++kk) {
      bf16x8 av[4], bv[4];
#pragma unroll
      for (int m = 0; m < 4; ++m) {
        int ra = wm * 64 + m * 16 + rlo;
        int pc = (kk * 4 + khi) ^ (ra & 7);
        av[m] = *reinterpret_cast<const bf16x8*>((const char*)la + ra * 128 + pc * 16);
      }
#pragma unroll
      for (int n = 0; n < 4; ++n) {
        int rb = wn * 64 + n * 16 + rlo;
        int pc = (kk * 4 + khi) ^ (rb & 7);
        bv[n] = *reinterpret_cast<const bf16x8*>((const char*)lb + rb * 128 + pc * 16);
      }
#pragma unroll
      for (int m = 0; m < 4; ++m)
#pragma unroll
        for (int n = 0; n < 4; ++n)
          acc[m][n] = __builtin_amdgcn_mfma_f32_16x16x32_bf16(av[m], bv[n], acc[m][n], 0, 0, 0);
    }
  }

  int obm = bm + wm * 64;
  int obn = bn + wn * 64;
  int crow = (lane >> 4) * 4;
  int ccol = lane & 15;
#pragma unroll
  for (int n = 0; n < 4; ++n) {
    int c = obn + n * 16 + ccol;
    float bc = (MODE == 2) ? 0.f : bias[c];
#pragma unroll
    for (int m = 0; m < 4; ++m) {
#pragma unroll
      for (int v = 0; v < 4; ++v) {
        int r = obm + m * 16 + crow + v;
        size_t idx = (size_t)r * N + c;
        float val = acc[m][n][v];
        if (MODE == 0) {
          float pvl = val + bc;
          out0[idx] = pvl;
          float e = pvl > 0.f ? pvl : expm1f(pvl);
          out1bf[idx] = (short)f2bf(e);
        } else if (MODE == 1) {
          float pvl = val + bc;
          out0[idx] = resid[idx] + 0.4f * (pvl > 0.f ? pvl : expm1f(pvl));
        } else {
          out0[idx] = val > 0.f ? val : 0.f;
        }
      }
    }
  }
}

extern "C" void kernel_launch(void* const* d_in, const int* in_sizes, int n_in,
                              void* d_out, int out_size, void* d_ws, size_t ws_size,
                              hipStream_t stream) {
  const float* x  = (const float*)d_in[0];
  const int* rows = (const int*)d_in[1];
  const int* cols = (const int*)d_in[2];
  const float* vals = (const float*)d_in[3];
  const float* W1 = (const float*)d_in[4];
  const float* b1 = (const float*)d_in[5];
  const float* W2 = (const float*)d_in[6];
  const float* b2 = (const float*)d_in[7];

  float* out_adj = (float*)d_out;
  float* out_hid = out_adj + (size_t)N_NODES * N_NODES;

  char* w = (char*)d_ws;
  size_t off = 0;
  auto alloc = [&](size_t bytes) -> void* {
    void* p = w + off;
    off += (bytes + 255) & ~(size_t)255;
    return p;
  };
  int* counts   = (int*)alloc(8192 * sizeof(int));
  int* offs     = (int*)alloc(8193 * sizeof(int));
  int* cursor   = (int*)alloc(8192 * sizeof(int));
  int2* edges   = (int2*)alloc((size_t)NEDGE * sizeof(int2));
  float* b12    = (float*)alloc(HDIM * sizeof(float));
  short* Xbf    = (short*)alloc((size_t)N_NODES * HDIM * sizeof(short));
  short* Tbf    = (short*)alloc((size_t)N_NODES * HDIM * sizeof(short));
  short* Abuf   = (short*)alloc((size_t)N_NODES * 1024 * sizeof(short));
  short* Bbuf   = (short*)alloc((size_t)512 * 1024 * sizeof(short));
  float* pre1   = (float*)alloc((size_t)N_NODES * HDIM * sizeof(float));
  float* Hf     = (float*)alloc((size_t)N_NODES * HDIM * sizeof(float));
  short* Hbuf   = (short*)alloc((size_t)N_NODES * HDIM * sizeof(short));

  // CSR build (packed (col,val) edge list, row-sorted)
  zero_kernel<<<32, 256, 0, stream>>>(counts);
  hist_kernel<<<NEDGE / 256, 256, 0, stream>>>(rows, counts);
  scan_kernel<<<1, 1024, 0, stream>>>(counts, offs, cursor);
  scatter_kernel<<<NEDGE / 256, 256, 0, stream>>>(rows, cols, vals, cursor, edges);

  // fused prep: x cast, W1/W2 cast, bias
  prep_kernel<<<2305, 256, 0, stream>>>(x, W1, W2, b1, b2, Xbf, Bbuf, b12);

  // ---- layer 1 ----
  spmm_bf<0><<<2048, 256, 0, stream>>>(offs, edges, Xbf, x, Abuf, Tbf);
  spmm_bf<2><<<2048, 256, 0, stream>>>(offs, edges, Tbf, nullptr, Abuf + 512, nullptr);
  // pre1 = [Ax|Axx]@[W1|W2]^T + b12 ; x1_bf = bf16(elu(pre1)) -> Xbf (reuse)
  gemm_lds<0><<<256, 256, 0, stream>>>(Abuf, Bbuf, 512, 1024, 4, b12, nullptr, pre1, Xbf);

  // ---- layer 2 ----
  spmm_bf<1><<<2048, 256, 0, stream>>>(offs, edges, Xbf, pre1, Abuf, Tbf);
  spmm_bf<2><<<2048, 256, 0, stream>>>(offs, edges, Tbf, nullptr, Abuf + 512, nullptr);
  // x2 = pre1 + 0.4*elu([Ax2|Axx2]@[W1|W2]^T + b12) -> Hf
  gemm_lds<1><<<256, 256, 0, stream>>>(Abuf, Bbuf, 512, 1024, 4, b12, pre1, Hf, nullptr);

  // ---- decoder ----
  rownorm_kernel<<<2048, 256, 0, stream>>>(Hf, out_hid, Hbuf);
  gemm_lds<2><<<4096, 256, 0, stream>>>(Hbuf, Hbuf, 8192, 512, 64, nullptr, nullptr, out_adj, nullptr);
}